// Round 2
// baseline (886.589 us; speedup 1.0000x reference)
//
#include <hip/hip_runtime.h>
#include <hip/hip_bf16.h>
#include <cstdint>
#include <cstddef>

#define N_SPATIAL_C 65160
#define N_SPHERE_C  2883
#define N_EDGES_C   131072

typedef short bf16x8 __attribute__((ext_vector_type(8)));
typedef float f32x4  __attribute__((ext_vector_type(4)));

__device__ inline float bf2f(ushort u) {
    union { uint u; float f; } c; c.u = ((uint)u) << 16; return c.f;
}
__device__ inline ushort f2bf(float f) {
    __hip_bfloat16 h = __float2bfloat16(f);
    union { __hip_bfloat16 h; ushort u; } c; c.h = h; return c.u;
}
__device__ inline void storeO(float* p, float y)  { *p = y; }
__device__ inline void storeO(ushort* p, float y) { *p = f2bf(y); }

// ---------------------------------------------------------------------------
// MFMA GEMM: C(M x 256) = A(M x K, bf16 row-major) @ Bt(256 x K, bf16 = B^T)
// Block: 256 thr = 4 waves; tile 32 rows x 256 cols (full row -> LN fusable).
// Wave w owns cols [w*64, w*64+64); 2 row-tiles x 4 col-tiles of 16x16x32 MFMA.
// EPI: 0 = [+bias] write; 1 = +bias, relu, LN(g,o); 2 = +bias +P[senders]+R[rid], relu, LN
// EPI==2 may run in-place (C==A): block reads only its own 32 rows; syncthreads
// separates all reads from writes.
// ---------------------------------------------------------------------------
template<int EPI, typename OutT>
__global__ __launch_bounds__(256) void mfma_gemm(
    const ushort* __restrict__ A, const ushort* __restrict__ Bt,
    OutT* __restrict__ C, int M, int K,
    const float* __restrict__ bias,
    const float* __restrict__ g, const float* __restrict__ o,
    const ushort* __restrict__ P, const int* __restrict__ senders,
    const ushort* __restrict__ R, const int* __restrict__ receivers)
{
    const int m0   = blockIdx.x * 32;
    const int w    = threadIdx.x >> 6;
    const int lane = threadIdx.x & 63;
    const int lo   = lane & 15, hi = lane >> 4;

    f32x4 acc[2][4];
#pragma unroll
    for (int rt = 0; rt < 2; ++rt)
#pragma unroll
        for (int ct = 0; ct < 4; ++ct)
#pragma unroll
            for (int j = 0; j < 4; ++j) acc[rt][ct][j] = 0.f;

    for (int k0 = 0; k0 < K; k0 += 32) {
        bf16x8 a[2], b[4];
#pragma unroll
        for (int rt = 0; rt < 2; ++rt) {
            int r = m0 + rt * 16 + lo;
            if (r < M) {
                a[rt] = *reinterpret_cast<const bf16x8*>(A + (size_t)r * K + k0 + hi * 8);
            } else {
#pragma unroll
                for (int j = 0; j < 8; ++j) a[rt][j] = 0;
            }
        }
#pragma unroll
        for (int ct = 0; ct < 4; ++ct) {
            int c = w * 64 + ct * 16 + lo;
            b[ct] = *reinterpret_cast<const bf16x8*>(Bt + (size_t)c * K + k0 + hi * 8);
        }
#pragma unroll
        for (int rt = 0; rt < 2; ++rt)
#pragma unroll
            for (int ct = 0; ct < 4; ++ct)
                acc[rt][ct] = __builtin_amdgcn_mfma_f32_16x16x32_bf16(
                    a[rt], b[ct], acc[rt][ct], 0, 0, 0);
    }

    __syncthreads();   // in-place safety (EPI==2): all A reads done before writes

    if (EPI == 0) {
#pragma unroll
        for (int rt = 0; rt < 2; ++rt)
#pragma unroll
            for (int reg = 0; reg < 4; ++reg) {
                int row = m0 + rt * 16 + hi * 4 + reg;
                if (row < M) {
#pragma unroll
                    for (int ct = 0; ct < 4; ++ct) {
                        int col = w * 64 + ct * 16 + lo;
                        float y = acc[rt][ct][reg];
                        if (bias) y += bias[col];
                        storeO(&C[(size_t)row * 256 + col], y);
                    }
                }
            }
    } else {
        __shared__ float red1[32][4];
        __shared__ float red2[32][4];
        float x[2][4][4];
#pragma unroll
        for (int rt = 0; rt < 2; ++rt)
#pragma unroll
            for (int reg = 0; reg < 4; ++reg) {
                int rowl = rt * 16 + hi * 4 + reg;
                int rowg = m0 + rowl;
                int sIdx = 0, rIdx = 0;
                bool ok = (rowg < M);
                if (EPI == 2 && ok) {
                    sIdx = senders[rowg];
                    rIdx = receivers[rowg] - N_SPATIAL_C;
                }
                float a1 = 0.f, a2 = 0.f;
#pragma unroll
                for (int ct = 0; ct < 4; ++ct) {
                    int col = w * 64 + ct * 16 + lo;
                    float y = acc[rt][ct][reg] + bias[col];
                    if (EPI == 2 && ok)
                        y += bf2f(P[(size_t)sIdx * 256 + col]) +
                             bf2f(R[(size_t)rIdx * 256 + col]);
                    y = fmaxf(y, 0.f);
                    x[rt][ct][reg] = y;
                    a1 += y; a2 += y * y;
                }
#pragma unroll
                for (int m = 1; m < 16; m <<= 1) {
                    a1 += __shfl_xor(a1, m);
                    a2 += __shfl_xor(a2, m);
                }
                if (lo == 0) { red1[rowl][w] = a1; red2[rowl][w] = a2; }
            }
        __syncthreads();
#pragma unroll
        for (int rt = 0; rt < 2; ++rt)
#pragma unroll
            for (int reg = 0; reg < 4; ++reg) {
                int rowl = rt * 16 + hi * 4 + reg;
                int rowg = m0 + rowl;
                float t1 = red1[rowl][0] + red1[rowl][1] + red1[rowl][2] + red1[rowl][3];
                float t2 = red2[rowl][0] + red2[rowl][1] + red2[rowl][2] + red2[rowl][3];
                float mean = t1 * (1.f / 256.f);
                float var  = t2 * (1.f / 256.f) - mean * mean;
                float rstd = rsqrtf(var + 1e-5f);
                if (rowg < M) {
#pragma unroll
                    for (int ct = 0; ct < 4; ++ct) {
                        int col = w * 64 + ct * 16 + lo;
                        float y = (x[rt][ct][reg] - mean) * rstd * g[col] + o[col];
                        storeO(&C[(size_t)rowg * 256 + col], y);
                    }
                }
            }
    }
}

// ---------------------------------------------------------------------------
// Step-0 edge fuse: H = LN(relu(edges3@Ae + P0[s] + R[rid] + be1)) * g + o
// One wave per row (64 lanes x 4 cols), 4 rows/block.
// ---------------------------------------------------------------------------
__global__ __launch_bounds__(256) void fuse0(
    const float* __restrict__ edges3, const float* __restrict__ Ae,
    const ushort* __restrict__ P, const int* __restrict__ senders,
    const ushort* __restrict__ R, const int* __restrict__ receivers,
    const float* __restrict__ be1, const float* __restrict__ g,
    const float* __restrict__ o, ushort* __restrict__ H)
{
    int row  = blockIdx.x * 4 + (threadIdx.x >> 6);
    int lane = threadIdx.x & 63;
    int c = lane * 4;

    float e0 = edges3[(size_t)row * 3 + 0];
    float e1 = edges3[(size_t)row * 3 + 1];
    float e2 = edges3[(size_t)row * 3 + 2];
    int s = senders[row];
    int r = receivers[row] - N_SPATIAL_C;
    ushort4 pv = *reinterpret_cast<const ushort4*>(P + (size_t)s * 256 + c);
    ushort4 rv = *reinterpret_cast<const ushort4*>(R + (size_t)r * 256 + c);

    float x[4];
    float pw[4] = {bf2f(pv.x), bf2f(pv.y), bf2f(pv.z), bf2f(pv.w)};
    float rw[4] = {bf2f(rv.x), bf2f(rv.y), bf2f(rv.z), bf2f(rv.w)};
#pragma unroll
    for (int j = 0; j < 4; ++j) {
        x[j] = e0 * Ae[c + j] + e1 * Ae[256 + c + j] + e2 * Ae[512 + c + j]
             + be1[c + j] + pw[j] + rw[j];
        x[j] = fmaxf(x[j], 0.f);
    }
    float s1 = x[0] + x[1] + x[2] + x[3];
    float s2 = x[0]*x[0] + x[1]*x[1] + x[2]*x[2] + x[3]*x[3];
#pragma unroll
    for (int m = 32; m > 0; m >>= 1) { s1 += __shfl_xor(s1, m); s2 += __shfl_xor(s2, m); }
    float mean = s1 * (1.f / 256.f);
    float var  = s2 * (1.f / 256.f) - mean * mean;
    float rstd = rsqrtf(var + 1e-5f);
#pragma unroll
    for (int j = 0; j < 4; ++j) {
        float y = (x[j] - mean) * rstd * g[c + j] + o[c + j];
        H[(size_t)row * 256 + c + j] = f2bf(y);
    }
}

// ---------------------------------------------------------------------------
// CSR build (receivers fixed across all steps)
// ---------------------------------------------------------------------------
__global__ void count_k(const int* __restrict__ receivers, int* __restrict__ cnt)
{
    int e = blockIdx.x * 256 + threadIdx.x;
    if (e < N_EDGES_C) atomicAdd(&cnt[receivers[e] - N_SPATIAL_C], 1);
}

__global__ void scan_k(const int* __restrict__ cnt, int* __restrict__ row_start)
{
    __shared__ int sums[257];
    const int CH = 12;
    int t = threadIdx.x;
    int local = 0;
    for (int i = 0; i < CH; ++i) {
        int idx = t * CH + i;
        if (idx < N_SPHERE_C) local += cnt[idx];
    }
    sums[t] = local;
    __syncthreads();
    if (t == 0) {
        int run = 0;
        for (int i = 0; i < 256; ++i) { int v = sums[i]; sums[i] = run; run += v; }
        sums[256] = run;
    }
    __syncthreads();
    int base = sums[t];
    for (int i = 0; i < CH; ++i) {
        int idx = t * CH + i;
        if (idx < N_SPHERE_C) { row_start[idx] = base; base += cnt[idx]; }
    }
    if (t == 0) row_start[N_SPHERE_C] = sums[256];
}

__global__ void fill_k(const int* __restrict__ receivers, const int* __restrict__ row_start,
                       int* __restrict__ cursor, int* __restrict__ csr)
{
    int e = blockIdx.x * 256 + threadIdx.x;
    if (e < N_EDGES_C) {
        int rid = receivers[e] - N_SPATIAL_C;
        int pos = atomicAdd(&cursor[rid], 1);
        csr[row_start[rid] + pos] = e;
    }
}

// S_bf[n][d] = bf16( sum_{e in seg(n)} H[e][d] )
__global__ void seg_gather(const ushort* __restrict__ H, const int* __restrict__ row_start,
                           const int* __restrict__ csr, ushort* __restrict__ S)
{
    int n = blockIdx.x, d = threadIdx.x;
    int beg = row_start[n], end = row_start[n + 1];
    float acc = 0.f;
    for (int i = beg; i < end; ++i)
        acc += bf2f(H[(size_t)csr[i] * 256 + d]);
    S[(size_t)n * 256 + d] = f2bf(acc);
}

// node_in = [sphere_bf | bf16(Mmsg + cnt*be2)]
__global__ void node_assemble(const ushort* __restrict__ sphere, const float* __restrict__ Mmsg,
                              const int* __restrict__ cnt, const float* __restrict__ be2,
                              ushort* __restrict__ node_in)
{
    int n = blockIdx.x, d = threadIdx.x;
    node_in[(size_t)n * 512 + d] = sphere[(size_t)n * 256 + d];
    node_in[(size_t)n * 512 + 256 + d] =
        f2bf(Mmsg[(size_t)n * 256 + d] + (float)cnt[n] * be2[d]);
}

// Wft[j][k] = bf16( (We2 @ Be)[k][j] )
__global__ __launch_bounds__(256) void wf_kernel(
    const float* __restrict__ We2, const float* __restrict__ Be, ushort* __restrict__ Wft)
{
    __shared__ float colB[256];
    int j = blockIdx.x, k = threadIdx.x;
    colB[k] = Be[(size_t)k * 256 + j];
    __syncthreads();
    const float* wrow = We2 + (size_t)k * 256;
    float acc = 0.f;
    for (int t = 0; t < 256; ++t) acc += wrow[t] * colB[t];
    Wft[(size_t)j * 256 + k] = f2bf(acc);
}

// bfc[j] = be1[j] + sum_k be2[k] * Be[k][j]
__global__ void bf_kernel(const float* __restrict__ be1, const float* __restrict__ be2,
                          const float* __restrict__ Be, float* __restrict__ bfc)
{
    int j = threadIdx.x;
    float acc = be1[j];
    for (int k = 0; k < 256; ++k) acc += be2[k] * Be[(size_t)k * 256 + j];
    bfc[j] = acc;
}

// Wt[n][k] = bf16(W[k][n]);  W: K x 256 row-major
__global__ void tcast(const float* __restrict__ W, ushort* __restrict__ Wt, int K)
{
    __shared__ float t[16][17];
    int k0 = blockIdx.x * 16, n0 = blockIdx.y * 16;
    int tx = threadIdx.x, ty = threadIdx.y;
    t[ty][tx] = W[(size_t)(k0 + ty) * 256 + n0 + tx];
    __syncthreads();
    Wt[(size_t)(n0 + ty) * K + k0 + tx] = f2bf(t[tx][ty]);
}

__global__ void cast_f32_bf16(const float* __restrict__ src, ushort* __restrict__ dst, int n4)
{
    int i = blockIdx.x * 256 + threadIdx.x;
    if (i < n4) {
        float4 v = *reinterpret_cast<const float4*>(src + (size_t)i * 4);
        ushort4 u;
        u.x = f2bf(v.x); u.y = f2bf(v.y); u.z = f2bf(v.z); u.w = f2bf(v.w);
        *reinterpret_cast<ushort4*>(dst + (size_t)i * 4) = u;
    }
}

// ---------------------------------------------------------------------------
extern "C" void kernel_launch(void* const* d_in, const int* in_sizes, int n_in,
                              void* d_out, int out_size, void* d_ws, size_t ws_size,
                              hipStream_t stream)
{
    const float* nodes     = (const float*)d_in[0];
    const float* edges3    = (const float*)d_in[1];
    const int*   senders   = (const int*)d_in[2];
    const int*   receivers = (const int*)d_in[3];
    const float* We1a      = (const float*)d_in[4];
    const float* We1b      = (const float*)d_in[5];
    const float* be1       = (const float*)d_in[6];
    const float* ge        = (const float*)d_in[7];
    const float* oe        = (const float*)d_in[8];
    const float* We2       = (const float*)d_in[9];
    const float* be2       = (const float*)d_in[10];
    const float* Wn1       = (const float*)d_in[11];
    const float* bn1       = (const float*)d_in[12];
    const float* gn        = (const float*)d_in[13];
    const float* on_       = (const float*)d_in[14];
    const float* Wn2       = (const float*)d_in[15];
    const float* bn2       = (const float*)d_in[16];

    const float* Ae  = We1a;               // rows 0..2
    const float* As_ = We1a + 3 * 256;     // sender part, step 0
    const float* Ar  = We1a + 259 * 256;   // receiver part, step 0
    const float* Be  = We1b;               // edge part, steps 1,2
    const float* Bs_ = We1b + 256 * 256;   // sender part, steps 1,2
    const float* Br  = We1b + 512 * 256;   // receiver part, steps 1,2

    char* ws = (char*)d_ws;
    size_t off = 0;
    auto alloc = [&](size_t b) -> char* {
        char* p = ws + off;
        off += (b + 255) & ~(size_t)255;
        return p;
    };
    // total ~146 MB
    ushort* H          = (ushort*)alloc((size_t)N_EDGES_C * 256 * 2);    // 67 MB
    ushort* Pb         = (ushort*)alloc((size_t)N_SPATIAL_C * 256 * 2);  // 33 MB
    ushort* nodes_bf   = (ushort*)alloc((size_t)N_SPATIAL_C * 256 * 2);  // 33 MB
    ushort* Rb         = (ushort*)alloc((size_t)N_SPHERE_C * 256 * 2);
    ushort* sphere_bf  = (ushort*)alloc((size_t)N_SPHERE_C * 256 * 2);
    ushort* S_bf       = (ushort*)alloc((size_t)N_SPHERE_C * 256 * 2);
    ushort* nH         = (ushort*)alloc((size_t)N_SPHERE_C * 256 * 2);
    ushort* node_in_bf = (ushort*)alloc((size_t)N_SPHERE_C * 512 * 2);
    float*  Mmsg       = (float*)alloc((size_t)N_SPHERE_C * 256 * 4);
    ushort* Ast  = (ushort*)alloc(256 * 256 * 2);
    ushort* Art  = (ushort*)alloc(256 * 256 * 2);
    ushort* Bst  = (ushort*)alloc(256 * 256 * 2);
    ushort* Brt  = (ushort*)alloc(256 * 256 * 2);
    ushort* We2t = (ushort*)alloc(256 * 256 * 2);
    ushort* Wn2t = (ushort*)alloc(256 * 256 * 2);
    ushort* Wn1t = (ushort*)alloc(512 * 256 * 2);
    ushort* Wft  = (ushort*)alloc(256 * 256 * 2);
    float*  bfc  = (float*)alloc(256 * 4);
    int* cnt       = (int*)alloc(N_SPHERE_C * 4);
    int* cursor    = (int*)alloc(N_SPHERE_C * 4);
    int* row_start = (int*)alloc((N_SPHERE_C + 1) * 4);
    int* csr       = (int*)alloc((size_t)N_EDGES_C * 4);

    // CSR build
    hipMemsetAsync(cnt, 0, N_SPHERE_C * 4, stream);
    hipMemsetAsync(cursor, 0, N_SPHERE_C * 4, stream);
    count_k<<<(N_EDGES_C + 255) / 256, 256, 0, stream>>>(receivers, cnt);
    scan_k<<<1, 256, 0, stream>>>(cnt, row_start);
    fill_k<<<(N_EDGES_C + 255) / 256, 256, 0, stream>>>(receivers, row_start, cursor, csr);

    // weight prep
    dim3 tb(16, 16);
    tcast<<<dim3(16, 16), tb, 0, stream>>>(As_, Ast, 256);
    tcast<<<dim3(16, 16), tb, 0, stream>>>(Ar,  Art, 256);
    tcast<<<dim3(16, 16), tb, 0, stream>>>(Bs_, Bst, 256);
    tcast<<<dim3(16, 16), tb, 0, stream>>>(Br,  Brt, 256);
    tcast<<<dim3(16, 16), tb, 0, stream>>>(We2, We2t, 256);
    tcast<<<dim3(16, 16), tb, 0, stream>>>(Wn2, Wn2t, 256);
    tcast<<<dim3(32, 16), tb, 0, stream>>>(Wn1, Wn1t, 512);
    wf_kernel<<<256, 256, 0, stream>>>(We2, Be, Wft);
    bf_kernel<<<1, 256, 0, stream>>>(be1, be2, Be, bfc);

    // input casts
    cast_f32_bf16<<<(N_SPATIAL_C * 64 + 255) / 256, 256, 0, stream>>>(
        nodes, nodes_bf, N_SPATIAL_C * 64);
    cast_f32_bf16<<<(N_SPHERE_C * 64 + 255) / 256, 256, 0, stream>>>(
        nodes + (size_t)N_SPATIAL_C * 256, sphere_bf, N_SPHERE_C * 64);

    // P0 = spatial @ As
    mfma_gemm<0, ushort><<<(N_SPATIAL_C + 31) / 32, 256, 0, stream>>>(
        nodes_bf, Ast, Pb, N_SPATIAL_C, 256,
        nullptr, nullptr, nullptr, nullptr, nullptr, nullptr, nullptr);

    for (int step = 0; step < 3; ++step) {
        // R = sphere @ W1_r
        mfma_gemm<0, ushort><<<(N_SPHERE_C + 31) / 32, 256, 0, stream>>>(
            sphere_bf, step == 0 ? Art : Brt, Rb, N_SPHERE_C, 256,
            nullptr, nullptr, nullptr, nullptr, nullptr, nullptr, nullptr);

        if (step == 0) {
            fuse0<<<N_EDGES_C / 4, 256, 0, stream>>>(
                edges3, Ae, Pb, senders, Rb, receivers, be1, ge, oe, H);
            // overwrite P with P12 = spatial @ Bs
            mfma_gemm<0, ushort><<<(N_SPATIAL_C + 31) / 32, 256, 0, stream>>>(
                nodes_bf, Bst, Pb, N_SPATIAL_C, 256,
                nullptr, nullptr, nullptr, nullptr, nullptr, nullptr, nullptr);
        } else {
            // H = LN(relu(H@Wf + P12[s] + R[rid] + bfc)) * ge + oe   (in-place)
            mfma_gemm<2, ushort><<<N_EDGES_C / 32, 256, 0, stream>>>(
                H, Wft, H, N_EDGES_C, 256,
                bfc, ge, oe, Pb, senders, Rb, receivers);
        }

        // messages path: S = segsum(H); Mmsg = S @ We2
        seg_gather<<<N_SPHERE_C, 256, 0, stream>>>(H, row_start, csr, S_bf);
        mfma_gemm<0, float><<<(N_SPHERE_C + 31) / 32, 256, 0, stream>>>(
            S_bf, We2t, Mmsg, N_SPHERE_C, 256,
            nullptr, nullptr, nullptr, nullptr, nullptr, nullptr, nullptr);
        node_assemble<<<N_SPHERE_C, 256, 0, stream>>>(sphere_bf, Mmsg, cnt, be2, node_in_bf);

        // node MLP
        mfma_gemm<1, ushort><<<(N_SPHERE_C + 31) / 32, 256, 0, stream>>>(
            node_in_bf, Wn1t, nH, N_SPHERE_C, 512,
            bn1, gn, on_, nullptr, nullptr, nullptr, nullptr);
        if (step < 2) {
            mfma_gemm<0, ushort><<<(N_SPHERE_C + 31) / 32, 256, 0, stream>>>(
                nH, Wn2t, sphere_bf, N_SPHERE_C, 256,
                bn2, nullptr, nullptr, nullptr, nullptr, nullptr, nullptr);
        } else {
            mfma_gemm<0, float><<<(N_SPHERE_C + 31) / 32, 256, 0, stream>>>(
                nH, Wn2t, (float*)d_out, N_SPHERE_C, 256,
                bn2, nullptr, nullptr, nullptr, nullptr, nullptr, nullptr);
        }
    }
}

// Round 3
// 677.585 us; speedup vs baseline: 1.3085x; 1.3085x over previous
//
#include <hip/hip_runtime.h>
#include <hip/hip_bf16.h>
#include <cstdint>
#include <cstddef>

#define N_SPATIAL_C 65160
#define N_SPHERE_C  2883
#define N_EDGES_C   131072

typedef short bf16x8 __attribute__((ext_vector_type(8)));
typedef float f32x4  __attribute__((ext_vector_type(4)));

__device__ inline float bf2f(ushort u) {
    union { uint u; float f; } c; c.u = ((uint)u) << 16; return c.f;
}
__device__ inline ushort f2bf(float f) {
    __hip_bfloat16 h = __float2bfloat16(f);
    union { __hip_bfloat16 h; ushort u; } c; c.h = h; return c.u;
}

// ---------------------------------------------------------------------------
// MFMA GEMM: C(M x 256) = A(M x KI, bf16 row-major) @ Bt(256 x KI, bf16 = B^T)
// Block: 256 thr = 4 waves; tile 64 rows x 256 cols.
// Stage: full 64 x KI A-tile -> LDS via global_load_lds(16B), XOR-swizzled
//        (linear LDS dest, inverse-swizzled per-lane global source).
// K-loop: fully unrolled; per wave per K-step: 4 ds_read_b128 (A) +
//         4 global 16B (B, L1/L2-hot) + 16 MFMA 16x16x32.
// Epilogue: 4 phases x 16 rows through LDS transpose (reuses A-tile LDS);
//         each thread owns 16 contiguous cols of one row -> vectorized
//         bias/g/o loads, P (bf16x8) / R (f32x4) gathers, coalesced stores.
// EPI: 0 = +bias store; 1 = +bias relu LN; 2 = +bias +P[send]+R[recv] relu LN.
// EPI==2 may run in place (C==A): all global A reads complete before the
// staging barrier; writes happen after.
// ---------------------------------------------------------------------------
template<int EPI, int KI, typename OutT>
__global__ __launch_bounds__(256, 2) void mfma_gemm(
    const ushort* __restrict__ A, const ushort* __restrict__ Bt,
    OutT* __restrict__ C, int M,
    const float* __restrict__ bias,
    const float* __restrict__ g, const float* __restrict__ o,
    const ushort* __restrict__ P, const int* __restrict__ senders,
    const float* __restrict__ Rf, const int* __restrict__ receivers)
{
    constexpr int CHR = KI / 8;            // 16B chunks per row
    __shared__ __align__(16) ushort Atile[64 * KI];   // 32KB (KI=256) / 64KB

    const int m0   = blockIdx.x * 64;
    const int t    = threadIdx.x;
    const int w    = t >> 6;
    const int lane = t & 63;
    const int lo   = lane & 15, hi = lane >> 4, sw = lo & 7;
    const int bn   = w * 64;

    // ---- stage A tile ----
#pragma unroll
    for (int i = 0; i < (64 * CHR) / 256; ++i) {
        int ci = i * 256 + t;
        int r  = ci / CHR;
        int cs = ci % CHR;
        int cg = cs ^ (r & 7);             // involution swizzle (within 128B)
        int rg = m0 + r; if (rg >= M) rg = M - 1;   // clamp (no fault; masked at store)
        const ushort* gp = A + (size_t)rg * KI + cg * 8;
        const ushort* lp = Atile + (size_t)(i * 256 + w * 64) * 8;  // wave-uniform base
        __builtin_amdgcn_global_load_lds(
            (const __attribute__((address_space(1))) unsigned int*)gp,
            (__attribute__((address_space(3))) unsigned int*)lp, 16, 0, 0);
    }
    __syncthreads();

    f32x4 acc[4][4];
#pragma unroll
    for (int rt = 0; rt < 4; ++rt)
#pragma unroll
        for (int ct = 0; ct < 4; ++ct)
#pragma unroll
            for (int j = 0; j < 4; ++j) acc[rt][ct][j] = 0.f;

    // ---- K loop (fully unrolled) ----
#pragma unroll
    for (int ks = 0; ks < KI / 32; ++ks) {
        bf16x8 av[4], bv[4];
#pragma unroll
        for (int rt = 0; rt < 4; ++rt) {
            int row = rt * 16 + lo;
            av[rt] = *reinterpret_cast<const bf16x8*>(
                Atile + ((size_t)row * CHR + ((ks * 4 + hi) ^ sw)) * 8);
        }
#pragma unroll
        for (int ct = 0; ct < 4; ++ct)
            bv[ct] = *reinterpret_cast<const bf16x8*>(
                Bt + (size_t)(bn + ct * 16 + lo) * KI + ks * 32 + hi * 8);
#pragma unroll
        for (int rt = 0; rt < 4; ++rt)
#pragma unroll
            for (int ct = 0; ct < 4; ++ct)
                acc[rt][ct] = __builtin_amdgcn_mfma_f32_16x16x32_bf16(
                    av[rt], bv[ct], acc[rt][ct], 0, 0, 0);
    }

    // ---- epilogue: 4 phases of 16 rows, transposed through LDS ----
    float* xbuf = reinterpret_cast<float*>(Atile);   // 16*260*4 = 16.6KB <= 32KB
    const int rl = t >> 4, q = t & 15, c0 = q * 16;

#pragma unroll
    for (int ph = 0; ph < 4; ++ph) {
        __syncthreads();                    // previous users of LDS done
#pragma unroll
        for (int ct = 0; ct < 4; ++ct)
#pragma unroll
            for (int reg = 0; reg < 4; ++reg)
                xbuf[(size_t)(hi * 4 + reg) * 260 + (bn + ct * 16 + lo)] =
                    acc[ph][ct][reg];
        __syncthreads();

        int rowg = m0 + ph * 16 + rl;
        bool ok  = rowg < M;
        int rowc = ok ? rowg : M - 1;

        float x[16];
#pragma unroll
        for (int jj = 0; jj < 4; ++jj) {
            f32x4 v = *reinterpret_cast<const f32x4*>(xbuf + (size_t)rl * 260 + c0 + jj * 4);
            x[jj*4+0] = v[0]; x[jj*4+1] = v[1]; x[jj*4+2] = v[2]; x[jj*4+3] = v[3];
        }
        if (bias) {
#pragma unroll
            for (int jj = 0; jj < 4; ++jj) {
                f32x4 v = *reinterpret_cast<const f32x4*>(bias + c0 + jj * 4);
                x[jj*4+0] += v[0]; x[jj*4+1] += v[1]; x[jj*4+2] += v[2]; x[jj*4+3] += v[3];
            }
        }
        if (EPI == 2) {
            int sIdx = senders[rowc];
            int rIdx = receivers[rowc] - N_SPATIAL_C;
            bf16x8 p0 = *reinterpret_cast<const bf16x8*>(P + (size_t)sIdx * 256 + c0);
            bf16x8 p1 = *reinterpret_cast<const bf16x8*>(P + (size_t)sIdx * 256 + c0 + 8);
#pragma unroll
            for (int j = 0; j < 8; ++j) {
                x[j]     += bf2f((ushort)p0[j]);
                x[8 + j] += bf2f((ushort)p1[j]);
            }
#pragma unroll
            for (int jj = 0; jj < 4; ++jj) {
                f32x4 v = *reinterpret_cast<const f32x4*>(Rf + (size_t)rIdx * 256 + c0 + jj * 4);
                x[jj*4+0] += v[0]; x[jj*4+1] += v[1]; x[jj*4+2] += v[2]; x[jj*4+3] += v[3];
            }
        }
        if (EPI >= 1) {
#pragma unroll
            for (int j = 0; j < 16; ++j) x[j] = fmaxf(x[j], 0.f);
            float s1 = 0.f, s2 = 0.f;
#pragma unroll
            for (int j = 0; j < 16; ++j) { s1 += x[j]; s2 += x[j] * x[j]; }
#pragma unroll
            for (int m = 1; m < 16; m <<= 1) {
                s1 += __shfl_xor(s1, m);
                s2 += __shfl_xor(s2, m);
            }
            float mean = s1 * (1.f / 256.f);
            float var  = s2 * (1.f / 256.f) - mean * mean;
            float rstd = rsqrtf(var + 1e-5f);
            float gg[16], oo[16];
#pragma unroll
            for (int jj = 0; jj < 4; ++jj) {
                f32x4 gv = *reinterpret_cast<const f32x4*>(g + c0 + jj * 4);
                f32x4 ov = *reinterpret_cast<const f32x4*>(o + c0 + jj * 4);
                gg[jj*4+0]=gv[0]; gg[jj*4+1]=gv[1]; gg[jj*4+2]=gv[2]; gg[jj*4+3]=gv[3];
                oo[jj*4+0]=ov[0]; oo[jj*4+1]=ov[1]; oo[jj*4+2]=ov[2]; oo[jj*4+3]=ov[3];
            }
#pragma unroll
            for (int j = 0; j < 16; ++j)
                x[j] = (x[j] - mean) * rstd * gg[j] + oo[j];
        }
        if (ok) {
            if constexpr (sizeof(OutT) == 2) {
                bf16x8 s0, s1;
#pragma unroll
                for (int j = 0; j < 8; ++j) {
                    s0[j] = (short)f2bf(x[j]);
                    s1[j] = (short)f2bf(x[8 + j]);
                }
                ushort* Cp = (ushort*)C + (size_t)rowg * 256 + c0;
                *reinterpret_cast<bf16x8*>(Cp)     = s0;
                *reinterpret_cast<bf16x8*>(Cp + 8) = s1;
            } else {
                float* Cp = (float*)C + (size_t)rowg * 256 + c0;
#pragma unroll
                for (int jj = 0; jj < 4; ++jj) {
                    f32x4 v;
                    v[0]=x[jj*4+0]; v[1]=x[jj*4+1]; v[2]=x[jj*4+2]; v[3]=x[jj*4+3];
                    *reinterpret_cast<f32x4*>(Cp + jj * 4) = v;
                }
            }
        }
    }
}

// ---------------------------------------------------------------------------
// Step-0 edge fuse: H = LN(relu(edges3@Ae + P0[s] + R[rid] + be1)) * g + o
// ---------------------------------------------------------------------------
__global__ __launch_bounds__(256) void fuse0(
    const float* __restrict__ edges3, const float* __restrict__ Ae,
    const ushort* __restrict__ P, const int* __restrict__ senders,
    const float* __restrict__ Rf, const int* __restrict__ receivers,
    const float* __restrict__ be1, const float* __restrict__ g,
    const float* __restrict__ o, ushort* __restrict__ H)
{
    int row  = blockIdx.x * 4 + (threadIdx.x >> 6);
    int lane = threadIdx.x & 63;
    int c = lane * 4;

    float e0 = edges3[(size_t)row * 3 + 0];
    float e1 = edges3[(size_t)row * 3 + 1];
    float e2 = edges3[(size_t)row * 3 + 2];
    int s = senders[row];
    int r = receivers[row] - N_SPATIAL_C;
    ushort4 pv = *reinterpret_cast<const ushort4*>(P + (size_t)s * 256 + c);
    float4  rv = *reinterpret_cast<const float4*>(Rf + (size_t)r * 256 + c);

    float pw[4] = {bf2f(pv.x), bf2f(pv.y), bf2f(pv.z), bf2f(pv.w)};
    float rw[4] = {rv.x, rv.y, rv.z, rv.w};
    float x[4];
#pragma unroll
    for (int j = 0; j < 4; ++j) {
        x[j] = e0 * Ae[c + j] + e1 * Ae[256 + c + j] + e2 * Ae[512 + c + j]
             + be1[c + j] + pw[j] + rw[j];
        x[j] = fmaxf(x[j], 0.f);
    }
    float s1 = x[0] + x[1] + x[2] + x[3];
    float s2 = x[0]*x[0] + x[1]*x[1] + x[2]*x[2] + x[3]*x[3];
#pragma unroll
    for (int m = 32; m > 0; m >>= 1) { s1 += __shfl_xor(s1, m); s2 += __shfl_xor(s2, m); }
    float mean = s1 * (1.f / 256.f);
    float var  = s2 * (1.f / 256.f) - mean * mean;
    float rstd = rsqrtf(var + 1e-5f);
#pragma unroll
    for (int j = 0; j < 4; ++j) {
        float y = (x[j] - mean) * rstd * g[c + j] + o[c + j];
        H[(size_t)row * 256 + c + j] = f2bf(y);
    }
}

// ---------------------------------------------------------------------------
// CSR build (receivers fixed across all steps)
// ---------------------------------------------------------------------------
__global__ void count_k(const int* __restrict__ receivers, int* __restrict__ cnt)
{
    int e = blockIdx.x * 256 + threadIdx.x;
    if (e < N_EDGES_C) atomicAdd(&cnt[receivers[e] - N_SPATIAL_C], 1);
}

__global__ void scan_k(const int* __restrict__ cnt, int* __restrict__ row_start)
{
    __shared__ int sums[257];
    const int CH = 12;
    int t = threadIdx.x;
    int local = 0;
    for (int i = 0; i < CH; ++i) {
        int idx = t * CH + i;
        if (idx < N_SPHERE_C) local += cnt[idx];
    }
    sums[t] = local;
    __syncthreads();
    if (t == 0) {
        int run = 0;
        for (int i = 0; i < 256; ++i) { int v = sums[i]; sums[i] = run; run += v; }
        sums[256] = run;
    }
    __syncthreads();
    int base = sums[t];
    for (int i = 0; i < CH; ++i) {
        int idx = t * CH + i;
        if (idx < N_SPHERE_C) { row_start[idx] = base; base += cnt[idx]; }
    }
    if (t == 0) row_start[N_SPHERE_C] = sums[256];
}

__global__ void fill_k(const int* __restrict__ receivers, const int* __restrict__ row_start,
                       int* __restrict__ cursor, int* __restrict__ csr)
{
    int e = blockIdx.x * 256 + threadIdx.x;
    if (e < N_EDGES_C) {
        int rid = receivers[e] - N_SPATIAL_C;
        int pos = atomicAdd(&cursor[rid], 1);
        csr[row_start[rid] + pos] = e;
    }
}

// S_bf[n][d] = bf16( sum_{e in seg(n)} H[e][d] ), 4-way row-parallel
__global__ __launch_bounds__(256) void seg_gather(
    const ushort* __restrict__ H, const int* __restrict__ row_start,
    const int* __restrict__ csr, ushort* __restrict__ S)
{
    __shared__ float red[3][64][4];
    int n = blockIdx.x;
    int sub = threadIdx.x >> 6, l = threadIdx.x & 63, c = l * 4;
    int beg = row_start[n], end = row_start[n + 1];
    float a0 = 0.f, a1 = 0.f, a2 = 0.f, a3 = 0.f;
    for (int i = beg + sub; i < end; i += 4) {
        int e = csr[i];
        ushort4 v = *reinterpret_cast<const ushort4*>(H + (size_t)e * 256 + c);
        a0 += bf2f(v.x); a1 += bf2f(v.y); a2 += bf2f(v.z); a3 += bf2f(v.w);
    }
    if (sub) { red[sub-1][l][0]=a0; red[sub-1][l][1]=a1; red[sub-1][l][2]=a2; red[sub-1][l][3]=a3; }
    __syncthreads();
    if (sub == 0) {
#pragma unroll
        for (int s_ = 0; s_ < 3; ++s_) {
            a0 += red[s_][l][0]; a1 += red[s_][l][1];
            a2 += red[s_][l][2]; a3 += red[s_][l][3];
        }
        ushort4 u; u.x = f2bf(a0); u.y = f2bf(a1); u.z = f2bf(a2); u.w = f2bf(a3);
        *reinterpret_cast<ushort4*>(S + (size_t)n * 256 + c) = u;
    }
}

// node_in = [sphere_bf | bf16(Mmsg + cnt*be2)]
__global__ void node_assemble(const ushort* __restrict__ sphere, const float* __restrict__ Mmsg,
                              const int* __restrict__ cnt, const float* __restrict__ be2,
                              ushort* __restrict__ node_in)
{
    int n = blockIdx.x, d = threadIdx.x;
    node_in[(size_t)n * 512 + d] = sphere[(size_t)n * 256 + d];
    node_in[(size_t)n * 512 + 256 + d] =
        f2bf(Mmsg[(size_t)n * 256 + d] + (float)cnt[n] * be2[d]);
}

// Wft[j][k] = bf16( (We2 @ Be)[k][j] )
__global__ __launch_bounds__(256) void wf_kernel(
    const float* __restrict__ We2, const float* __restrict__ Be, ushort* __restrict__ Wft)
{
    __shared__ float colB[256];
    int j = blockIdx.x, k = threadIdx.x;
    colB[k] = Be[(size_t)k * 256 + j];
    __syncthreads();
    const float* wrow = We2 + (size_t)k * 256;
    float acc = 0.f;
    for (int t = 0; t < 256; ++t) acc += wrow[t] * colB[t];
    Wft[(size_t)j * 256 + k] = f2bf(acc);
}

// bfc[j] = be1[j] + sum_k be2[k] * Be[k][j]
__global__ void bf_kernel(const float* __restrict__ be1, const float* __restrict__ be2,
                          const float* __restrict__ Be, float* __restrict__ bfc)
{
    int j = threadIdx.x;
    float acc = be1[j];
    for (int k = 0; k < 256; ++k) acc += be2[k] * Be[(size_t)k * 256 + j];
    bfc[j] = acc;
}

// Wt[n][k] = bf16(W[k][n]);  W: K x 256 row-major
__global__ void tcast(const float* __restrict__ W, ushort* __restrict__ Wt, int K)
{
    __shared__ float tbuf[16][17];
    int k0 = blockIdx.x * 16, n0 = blockIdx.y * 16;
    int tx = threadIdx.x, ty = threadIdx.y;
    tbuf[ty][tx] = W[(size_t)(k0 + ty) * 256 + n0 + tx];
    __syncthreads();
    Wt[(size_t)(n0 + ty) * K + k0 + tx] = f2bf(tbuf[tx][ty]);
}

__global__ void cast_f32_bf16(const float* __restrict__ src, ushort* __restrict__ dst, int n4)
{
    int i = blockIdx.x * 256 + threadIdx.x;
    if (i < n4) {
        float4 v = *reinterpret_cast<const float4*>(src + (size_t)i * 4);
        ushort4 u;
        u.x = f2bf(v.x); u.y = f2bf(v.y); u.z = f2bf(v.z); u.w = f2bf(v.w);
        *reinterpret_cast<ushort4*>(dst + (size_t)i * 4) = u;
    }
}

// ---------------------------------------------------------------------------
extern "C" void kernel_launch(void* const* d_in, const int* in_sizes, int n_in,
                              void* d_out, int out_size, void* d_ws, size_t ws_size,
                              hipStream_t stream)
{
    const float* nodes     = (const float*)d_in[0];
    const float* edges3    = (const float*)d_in[1];
    const int*   senders   = (const int*)d_in[2];
    const int*   receivers = (const int*)d_in[3];
    const float* We1a      = (const float*)d_in[4];
    const float* We1b      = (const float*)d_in[5];
    const float* be1       = (const float*)d_in[6];
    const float* ge        = (const float*)d_in[7];
    const float* oe        = (const float*)d_in[8];
    const float* We2       = (const float*)d_in[9];
    const float* be2       = (const float*)d_in[10];
    const float* Wn1       = (const float*)d_in[11];
    const float* bn1       = (const float*)d_in[12];
    const float* gn        = (const float*)d_in[13];
    const float* on_       = (const float*)d_in[14];
    const float* Wn2       = (const float*)d_in[15];
    const float* bn2       = (const float*)d_in[16];

    const float* Ae  = We1a;               // rows 0..2
    const float* As_ = We1a + 3 * 256;     // sender part, step 0
    const float* Ar  = We1a + 259 * 256;   // receiver part, step 0
    const float* Be  = We1b;               // edge part, steps 1,2
    const float* Bs_ = We1b + 256 * 256;   // sender part, steps 1,2
    const float* Br  = We1b + 512 * 256;   // receiver part, steps 1,2

    char* ws = (char*)d_ws;
    size_t off = 0;
    auto alloc = [&](size_t b) -> char* {
        char* p = ws + off;
        off += (b + 255) & ~(size_t)255;
        return p;
    };
    ushort* H          = (ushort*)alloc((size_t)N_EDGES_C * 256 * 2);    // 67 MB
    ushort* Pb         = (ushort*)alloc((size_t)N_SPATIAL_C * 256 * 2);  // 33 MB
    ushort* nodes_bf   = (ushort*)alloc((size_t)N_SPATIAL_C * 256 * 2);  // 33 MB
    float*  Rf         = (float*)alloc((size_t)N_SPHERE_C * 256 * 4);
    ushort* sphere_bf  = (ushort*)alloc((size_t)N_SPHERE_C * 256 * 2);
    ushort* S_bf       = (ushort*)alloc((size_t)N_SPHERE_C * 256 * 2);
    ushort* nH         = (ushort*)alloc((size_t)N_SPHERE_C * 256 * 2);
    ushort* node_in_bf = (ushort*)alloc((size_t)N_SPHERE_C * 512 * 2);
    float*  Mmsg       = (float*)alloc((size_t)N_SPHERE_C * 256 * 4);
    ushort* Ast  = (ushort*)alloc(256 * 256 * 2);
    ushort* Art  = (ushort*)alloc(256 * 256 * 2);
    ushort* Bst  = (ushort*)alloc(256 * 256 * 2);
    ushort* Brt  = (ushort*)alloc(256 * 256 * 2);
    ushort* We2t = (ushort*)alloc(256 * 256 * 2);
    ushort* Wn2t = (ushort*)alloc(256 * 256 * 2);
    ushort* Wn1t = (ushort*)alloc(512 * 256 * 2);
    ushort* Wft  = (ushort*)alloc(256 * 256 * 2);
    float*  bfc  = (float*)alloc(256 * 4);
    int* cnt       = (int*)alloc(N_SPHERE_C * 4);
    int* cursor    = (int*)alloc(N_SPHERE_C * 4);
    int* row_start = (int*)alloc((N_SPHERE_C + 1) * 4);
    int* csr       = (int*)alloc((size_t)N_EDGES_C * 4);

    // CSR build
    hipMemsetAsync(cnt, 0, N_SPHERE_C * 4, stream);
    hipMemsetAsync(cursor, 0, N_SPHERE_C * 4, stream);
    count_k<<<(N_EDGES_C + 255) / 256, 256, 0, stream>>>(receivers, cnt);
    scan_k<<<1, 256, 0, stream>>>(cnt, row_start);
    fill_k<<<(N_EDGES_C + 255) / 256, 256, 0, stream>>>(receivers, row_start, cursor, csr);

    // weight prep
    dim3 tb(16, 16);
    tcast<<<dim3(16, 16), tb, 0, stream>>>(As_, Ast, 256);
    tcast<<<dim3(16, 16), tb, 0, stream>>>(Ar,  Art, 256);
    tcast<<<dim3(16, 16), tb, 0, stream>>>(Bs_, Bst, 256);
    tcast<<<dim3(16, 16), tb, 0, stream>>>(Br,  Brt, 256);
    tcast<<<dim3(16, 16), tb, 0, stream>>>(We2, We2t, 256);
    tcast<<<dim3(16, 16), tb, 0, stream>>>(Wn2, Wn2t, 256);
    tcast<<<dim3(32, 16), tb, 0, stream>>>(Wn1, Wn1t, 512);
    wf_kernel<<<256, 256, 0, stream>>>(We2, Be, Wft);
    bf_kernel<<<1, 256, 0, stream>>>(be1, be2, Be, bfc);

    // input casts
    cast_f32_bf16<<<(N_SPATIAL_C * 64 + 255) / 256, 256, 0, stream>>>(
        nodes, nodes_bf, N_SPATIAL_C * 64);
    cast_f32_bf16<<<(N_SPHERE_C * 64 + 255) / 256, 256, 0, stream>>>(
        nodes + (size_t)N_SPATIAL_C * 256, sphere_bf, N_SPHERE_C * 64);

    const int GE = N_EDGES_C / 64;                 // 2048
    const int GP = (N_SPATIAL_C + 63) / 64;        // 1019
    const int GS = (N_SPHERE_C + 63) / 64;         // 46

    // P0 = spatial @ As
    mfma_gemm<0, 256, ushort><<<GP, 256, 0, stream>>>(
        nodes_bf, Ast, Pb, N_SPATIAL_C,
        nullptr, nullptr, nullptr, nullptr, nullptr, nullptr, nullptr);

    for (int step = 0; step < 3; ++step) {
        // R = sphere @ W1_r  (fp32 out)
        mfma_gemm<0, 256, float><<<GS, 256, 0, stream>>>(
            sphere_bf, step == 0 ? Art : Brt, Rf, N_SPHERE_C,
            nullptr, nullptr, nullptr, nullptr, nullptr, nullptr, nullptr);

        if (step == 0) {
            fuse0<<<N_EDGES_C / 4, 256, 0, stream>>>(
                edges3, Ae, Pb, senders, Rf, receivers, be1, ge, oe, H);
            // overwrite P with P12 = spatial @ Bs
            mfma_gemm<0, 256, ushort><<<GP, 256, 0, stream>>>(
                nodes_bf, Bst, Pb, N_SPATIAL_C,
                nullptr, nullptr, nullptr, nullptr, nullptr, nullptr, nullptr);
        } else {
            // H = LN(relu(H@Wf + P12[s] + R[rid] + bfc)) * ge + oe   (in-place)
            mfma_gemm<2, 256, ushort><<<GE, 256, 0, stream>>>(
                H, Wft, H, N_EDGES_C,
                bfc, ge, oe, Pb, senders, Rf, receivers);
        }

        // messages path: S = segsum(H); Mmsg = S @ We2
        seg_gather<<<N_SPHERE_C, 256, 0, stream>>>(H, row_start, csr, S_bf);
        mfma_gemm<0, 256, float><<<GS, 256, 0, stream>>>(
            S_bf, We2t, Mmsg, N_SPHERE_C,
            nullptr, nullptr, nullptr, nullptr, nullptr, nullptr, nullptr);
        node_assemble<<<N_SPHERE_C, 256, 0, stream>>>(sphere_bf, Mmsg, cnt, be2, node_in_bf);

        // node MLP
        mfma_gemm<1, 512, ushort><<<GS, 256, 0, stream>>>(
            node_in_bf, Wn1t, nH, N_SPHERE_C,
            bn1, gn, on_, nullptr, nullptr, nullptr, nullptr);
        if (step < 2) {
            mfma_gemm<0, 256, ushort><<<GS, 256, 0, stream>>>(
                nH, Wn2t, sphere_bf, N_SPHERE_C,
                bn2, nullptr, nullptr, nullptr, nullptr, nullptr, nullptr);
        } else {
            mfma_gemm<0, 256, float><<<GS, 256, 0, stream>>>(
                nH, Wn2t, (float*)d_out, N_SPHERE_C,
                bn2, nullptr, nullptr, nullptr, nullptr, nullptr, nullptr);
        }
    }
}

// Round 4
// 665.919 us; speedup vs baseline: 1.3314x; 1.0175x over previous
//
#include <hip/hip_runtime.h>
#include <hip/hip_bf16.h>
#include <cstdint>
#include <cstddef>

#define N_SPATIAL_C 65160
#define N_SPHERE_C  2883
#define N_EDGES_C   131072

typedef short bf16x8 __attribute__((ext_vector_type(8)));
typedef float f32x4  __attribute__((ext_vector_type(4)));

__device__ inline float bf2f(ushort u) {
    union { uint u; float f; } c; c.u = ((uint)u) << 16; return c.f;
}
__device__ inline ushort f2bf(float f) {
    __hip_bfloat16 h = __float2bfloat16(f);
    union { __hip_bfloat16 h; ushort u; } c; c.h = h; return c.u;
}

#define VMWAIT8()  asm volatile("s_waitcnt vmcnt(8)" ::: "memory")
#define VMWAIT0()  asm volatile("s_waitcnt vmcnt(0)" ::: "memory")
#define LGKM0()    asm volatile("s_waitcnt lgkmcnt(0)" ::: "memory")
#define SBAR()     do { __builtin_amdgcn_sched_barrier(0); \
                        __builtin_amdgcn_s_barrier(); \
                        __builtin_amdgcn_sched_barrier(0); } while (0)

// ---------------------------------------------------------------------------
// Persistent double-buffered MFMA GEMM.
// C(M x 256) = A(M x KI bf16, row stride lda) @ Bt(256 x KI bf16 = B^T)
// Block: 4 waves; tile 64 rows x 256 cols; grid-stride persistent over tiles.
// NBUF=2 (KI=256): LDS double-buffer, STAGE(next) issued before compute,
//   counted vmcnt(8); B operand held in registers (loaded once per block) so
//   the K-loop has no vmem -> staging overlaps compute (in-order vmcnt).
// NBUF=1 (KI=512): single buffer, stage-wait-compute per tile.
// EPI: 0 = +bias store; 1 = +bias [+cnt*bx] relu LN; 2 = +bias+P[s]+R[r] relu LN.
// EPI==2 may run in place (C==A): tiles own disjoint rows; within a block all
// reads of a tile precede its writes.
// ---------------------------------------------------------------------------
template<int EPI, int KI, int NBUF, typename OutT>
__global__ __launch_bounds__(256, 2) void mfma_gemm(
    const ushort* __restrict__ A, const ushort* __restrict__ Bt,
    OutT* __restrict__ C, int M, int lda, int ldc,
    const float* __restrict__ bias,
    const float* __restrict__ g, const float* __restrict__ o,
    const ushort* __restrict__ P, const int* __restrict__ senders,
    const float* __restrict__ Rf, const int* __restrict__ receivers,
    const int* __restrict__ cntv, const float* __restrict__ bxv)
{
    constexpr int CHR = KI / 8;                 // 16B chunks per row
    __shared__ __align__(16) ushort lds[NBUF][64 * KI];

    const int nt = (M + 63) >> 6;
    if ((int)blockIdx.x >= nt) return;
    const int G    = gridDim.x;
    const int t    = threadIdx.x;
    const int w    = t >> 6;
    const int lane = t & 63;
    const int lo   = lane & 15, hi = lane >> 4, sw = lo & 7;
    const int bn   = w * 64;
    const int rl   = t >> 4, q = t & 15, c0 = q * 16;

    auto STAGE = [&](int buf, int tileIdx) {
#pragma unroll
        for (int i = 0; i < (64 * CHR) / 256; ++i) {
            int ci = i * 256 + t;
            int r  = ci / CHR;
            int cs = ci % CHR;
            int cg = cs ^ (r & 7);              // involution swizzle (128B window)
            int rg = tileIdx * 64 + r; if (rg >= M) rg = M - 1;
            const ushort* gp = A + (size_t)rg * lda + cg * 8;
            const ushort* lp = &lds[buf][(size_t)(i * 256 + w * 64) * 8];
            __builtin_amdgcn_global_load_lds(
                (const __attribute__((address_space(1))) unsigned int*)gp,
                (__attribute__((address_space(3))) unsigned int*)lp, 16, 0, 0);
        }
    };

    // B operand in registers (NBUF==2 path): 32 x 16B, loaded once per block.
    bf16x8 breg[(NBUF == 2) ? 8 : 1][4];
    if constexpr (NBUF == 2) {
#pragma unroll
        for (int ks = 0; ks < 8; ++ks)
#pragma unroll
            for (int ct = 0; ct < 4; ++ct)
                breg[ks][ct] = *reinterpret_cast<const bf16x8*>(
                    Bt + (size_t)(bn + ct * 16 + lo) * KI + ks * 32 + hi * 8);
        STAGE(0, blockIdx.x);
    }

    int cur = 0;
    for (int tt = blockIdx.x; tt < nt; tt += G) {
        if constexpr (NBUF == 1) {
            STAGE(0, tt);
            VMWAIT0();
        } else {
            int tn = tt + G;
            if (tn < nt) { STAGE(cur ^ 1, tn); VMWAIT8(); }
            else         { VMWAIT0(); }
        }
        SBAR();

        const ushort* At = lds[cur];
        f32x4 acc[4][4];
#pragma unroll
        for (int rt = 0; rt < 4; ++rt)
#pragma unroll
            for (int ct = 0; ct < 4; ++ct)
#pragma unroll
                for (int j = 0; j < 4; ++j) acc[rt][ct][j] = 0.f;

#pragma unroll
        for (int ks = 0; ks < KI / 32; ++ks) {
            bf16x8 av[4], bv[4];
#pragma unroll
            for (int rt = 0; rt < 4; ++rt) {
                int row = rt * 16 + lo;
                av[rt] = *reinterpret_cast<const bf16x8*>(
                    At + ((size_t)row * CHR + ((ks * 4 + hi) ^ sw)) * 8);
            }
            if constexpr (NBUF == 2) {
#pragma unroll
                for (int ct = 0; ct < 4; ++ct) bv[ct] = breg[ks][ct];
            } else {
#pragma unroll
                for (int ct = 0; ct < 4; ++ct)
                    bv[ct] = *reinterpret_cast<const bf16x8*>(
                        Bt + (size_t)(bn + ct * 16 + lo) * KI + ks * 32 + hi * 8);
            }
#pragma unroll
            for (int rt = 0; rt < 4; ++rt)
#pragma unroll
                for (int ct = 0; ct < 4; ++ct)
                    acc[rt][ct] = __builtin_amdgcn_mfma_f32_16x16x32_bf16(
                        av[rt], bv[ct], acc[rt][ct], 0, 0, 0);
        }

        // ---- epilogue: 4 phases x 16 rows, transposed through lds[cur] ----
        float* xbuf = (float*)lds[cur];
#pragma unroll
        for (int ph = 0; ph < 4; ++ph) {
            LGKM0(); SBAR();                     // prior readers of lds[cur] done
#pragma unroll
            for (int ct = 0; ct < 4; ++ct)
#pragma unroll
                for (int reg = 0; reg < 4; ++reg)
                    xbuf[(size_t)(hi * 4 + reg) * 260 + (bn + ct * 16 + lo)] =
                        acc[ph][ct][reg];
            LGKM0(); SBAR();

            int rowg = tt * 64 + ph * 16 + rl;
            bool ok  = rowg < M;
            int rowc = ok ? rowg : M - 1;

            float x[16];
#pragma unroll
            for (int jj = 0; jj < 4; ++jj) {
                f32x4 v = *reinterpret_cast<const f32x4*>(
                    xbuf + (size_t)rl * 260 + c0 + jj * 4);
                x[jj*4+0] = v[0]; x[jj*4+1] = v[1];
                x[jj*4+2] = v[2]; x[jj*4+3] = v[3];
            }
            if (bias) {
#pragma unroll
                for (int jj = 0; jj < 4; ++jj) {
                    f32x4 v = *reinterpret_cast<const f32x4*>(bias + c0 + jj * 4);
                    x[jj*4+0] += v[0]; x[jj*4+1] += v[1];
                    x[jj*4+2] += v[2]; x[jj*4+3] += v[3];
                }
            }
            if (EPI == 1 && cntv) {
                float cf = (float)cntv[rowc];
#pragma unroll
                for (int jj = 0; jj < 4; ++jj) {
                    f32x4 v = *reinterpret_cast<const f32x4*>(bxv + c0 + jj * 4);
                    x[jj*4+0] += cf * v[0]; x[jj*4+1] += cf * v[1];
                    x[jj*4+2] += cf * v[2]; x[jj*4+3] += cf * v[3];
                }
            }
            if (EPI == 2) {
                int sIdx = senders[rowc];
                int rIdx = receivers[rowc] - N_SPATIAL_C;
                bf16x8 p0 = *reinterpret_cast<const bf16x8*>(P + (size_t)sIdx * 256 + c0);
                bf16x8 p1 = *reinterpret_cast<const bf16x8*>(P + (size_t)sIdx * 256 + c0 + 8);
#pragma unroll
                for (int j = 0; j < 8; ++j) {
                    x[j]     += bf2f((ushort)p0[j]);
                    x[8 + j] += bf2f((ushort)p1[j]);
                }
#pragma unroll
                for (int jj = 0; jj < 4; ++jj) {
                    f32x4 v = *reinterpret_cast<const f32x4*>(
                        Rf + (size_t)rIdx * 256 + c0 + jj * 4);
                    x[jj*4+0] += v[0]; x[jj*4+1] += v[1];
                    x[jj*4+2] += v[2]; x[jj*4+3] += v[3];
                }
            }
            if (EPI >= 1) {
#pragma unroll
                for (int j = 0; j < 16; ++j) x[j] = fmaxf(x[j], 0.f);
                float s1 = 0.f, s2 = 0.f;
#pragma unroll
                for (int j = 0; j < 16; ++j) { s1 += x[j]; s2 += x[j] * x[j]; }
#pragma unroll
                for (int m = 1; m < 16; m <<= 1) {
                    s1 += __shfl_xor(s1, m);
                    s2 += __shfl_xor(s2, m);
                }
                float mean = s1 * (1.f / 256.f);
                float var  = s2 * (1.f / 256.f) - mean * mean;
                float rstd = rsqrtf(var + 1e-5f);
#pragma unroll
                for (int jj = 0; jj < 4; ++jj) {
                    f32x4 gv = *reinterpret_cast<const f32x4*>(g + c0 + jj * 4);
                    f32x4 ov = *reinterpret_cast<const f32x4*>(o + c0 + jj * 4);
#pragma unroll
                    for (int e = 0; e < 4; ++e)
                        x[jj*4+e] = (x[jj*4+e] - mean) * rstd * gv[e] + ov[e];
                }
            }
            if (ok) {
                if constexpr (sizeof(OutT) == 2) {
                    bf16x8 s0, s1v;
#pragma unroll
                    for (int j = 0; j < 8; ++j) {
                        s0[j]  = (short)f2bf(x[j]);
                        s1v[j] = (short)f2bf(x[8 + j]);
                    }
                    ushort* Cp = (ushort*)C + (size_t)rowg * ldc + c0;
                    *reinterpret_cast<bf16x8*>(Cp)     = s0;
                    *reinterpret_cast<bf16x8*>(Cp + 8) = s1v;
                } else {
                    float* Cp = (float*)C + (size_t)rowg * ldc + c0;
#pragma unroll
                    for (int jj = 0; jj < 4; ++jj) {
                        f32x4 v;
                        v[0]=x[jj*4+0]; v[1]=x[jj*4+1];
                        v[2]=x[jj*4+2]; v[3]=x[jj*4+3];
                        *reinterpret_cast<f32x4*>(Cp + jj * 4) = v;
                    }
                }
            }
        }
        LGKM0(); SBAR();                          // lds[cur] free for restage
        if constexpr (NBUF == 2) cur ^= 1;
    }
}

// ---------------------------------------------------------------------------
// Step-0 edge fuse: H = LN(relu(edges3@Ae + P0[s] + R[rid] + be1)) * g + o
// ---------------------------------------------------------------------------
__global__ __launch_bounds__(256) void fuse0(
    const float* __restrict__ edges3, const float* __restrict__ Ae,
    const ushort* __restrict__ P, const int* __restrict__ senders,
    const float* __restrict__ Rf, const int* __restrict__ receivers,
    const float* __restrict__ be1, const float* __restrict__ g,
    const float* __restrict__ o, ushort* __restrict__ H)
{
    int row  = blockIdx.x * 4 + (threadIdx.x >> 6);
    int lane = threadIdx.x & 63;
    int c = lane * 4;

    float e0 = edges3[(size_t)row * 3 + 0];
    float e1 = edges3[(size_t)row * 3 + 1];
    float e2 = edges3[(size_t)row * 3 + 2];
    int s = senders[row];
    int r = receivers[row] - N_SPATIAL_C;
    ushort4 pv = *reinterpret_cast<const ushort4*>(P + (size_t)s * 256 + c);
    float4  rv = *reinterpret_cast<const float4*>(Rf + (size_t)r * 256 + c);

    float pw[4] = {bf2f(pv.x), bf2f(pv.y), bf2f(pv.z), bf2f(pv.w)};
    float rw[4] = {rv.x, rv.y, rv.z, rv.w};
    float x[4];
#pragma unroll
    for (int j = 0; j < 4; ++j) {
        x[j] = e0 * Ae[c + j] + e1 * Ae[256 + c + j] + e2 * Ae[512 + c + j]
             + be1[c + j] + pw[j] + rw[j];
        x[j] = fmaxf(x[j], 0.f);
    }
    float s1 = x[0] + x[1] + x[2] + x[3];
    float s2 = x[0]*x[0] + x[1]*x[1] + x[2]*x[2] + x[3]*x[3];
#pragma unroll
    for (int m = 32; m > 0; m >>= 1) { s1 += __shfl_xor(s1, m); s2 += __shfl_xor(s2, m); }
    float mean = s1 * (1.f / 256.f);
    float var  = s2 * (1.f / 256.f) - mean * mean;
    float rstd = rsqrtf(var + 1e-5f);
#pragma unroll
    for (int j = 0; j < 4; ++j) {
        float y = (x[j] - mean) * rstd * g[c + j] + o[c + j];
        H[(size_t)row * 256 + c + j] = f2bf(y);
    }
}

// ---------------------------------------------------------------------------
// CSR build (receivers fixed across all steps)
// ---------------------------------------------------------------------------
__global__ void count_k(const int* __restrict__ receivers, int* __restrict__ cnt)
{
    int e = blockIdx.x * 256 + threadIdx.x;
    if (e < N_EDGES_C) atomicAdd(&cnt[receivers[e] - N_SPATIAL_C], 1);
}

__global__ void scan_k(const int* __restrict__ cnt, int* __restrict__ row_start)
{
    __shared__ int sums[257];
    const int CH = 12;
    int t = threadIdx.x;
    int local = 0;
    for (int i = 0; i < CH; ++i) {
        int idx = t * CH + i;
        if (idx < N_SPHERE_C) local += cnt[idx];
    }
    sums[t] = local;
    __syncthreads();
    if (t == 0) {
        int run = 0;
        for (int i = 0; i < 256; ++i) { int v = sums[i]; sums[i] = run; run += v; }
        sums[256] = run;
    }
    __syncthreads();
    int base = sums[t];
    for (int i = 0; i < CH; ++i) {
        int idx = t * CH + i;
        if (idx < N_SPHERE_C) { row_start[idx] = base; base += cnt[idx]; }
    }
    if (t == 0) row_start[N_SPHERE_C] = sums[256];
}

__global__ void fill_k(const int* __restrict__ receivers, const int* __restrict__ row_start,
                       int* __restrict__ cursor, int* __restrict__ csr)
{
    int e = blockIdx.x * 256 + threadIdx.x;
    if (e < N_EDGES_C) {
        int rid = receivers[e] - N_SPATIAL_C;
        int pos = atomicAdd(&cursor[rid], 1);
        csr[row_start[rid] + pos] = e;
    }
}

// S[n][d] = bf16( sum_{e in seg(n)} H[e][d] ), output row stride ldS
__global__ __launch_bounds__(256) void seg_gather(
    const ushort* __restrict__ H, const int* __restrict__ row_start,
    const int* __restrict__ csr, ushort* __restrict__ S, int ldS)
{
    __shared__ float red[3][64][4];
    int n = blockIdx.x;
    int sub = threadIdx.x >> 6, l = threadIdx.x & 63, c = l * 4;
    int beg = row_start[n], end = row_start[n + 1];
    float a0 = 0.f, a1 = 0.f, a2 = 0.f, a3 = 0.f;
    for (int i = beg + sub; i < end; i += 4) {
        int e = csr[i];
        ushort4 v = *reinterpret_cast<const ushort4*>(H + (size_t)e * 256 + c);
        a0 += bf2f(v.x); a1 += bf2f(v.y); a2 += bf2f(v.z); a3 += bf2f(v.w);
    }
    if (sub) { red[sub-1][l][0]=a0; red[sub-1][l][1]=a1; red[sub-1][l][2]=a2; red[sub-1][l][3]=a3; }
    __syncthreads();
    if (sub == 0) {
#pragma unroll
        for (int s_ = 0; s_ < 3; ++s_) {
            a0 += red[s_][l][0]; a1 += red[s_][l][1];
            a2 += red[s_][l][2]; a3 += red[s_][l][3];
        }
        ushort4 u; u.x = f2bf(a0); u.y = f2bf(a1); u.z = f2bf(a2); u.w = f2bf(a3);
        *reinterpret_cast<ushort4*>(S + (size_t)n * ldS + c) = u;
    }
}

// Wft[j][k] = bf16( (We2 @ Bsrc)[k][j] )   (j=block, k=thread), dst stride ldd, offset koff
__global__ __launch_bounds__(256) void wprod_kernel(
    const float* __restrict__ We2, const float* __restrict__ Bsrc,
    ushort* __restrict__ Wt, int ldd, int koff)
{
    __shared__ float colB[256];
    int j = blockIdx.x, k = threadIdx.x;
    colB[k] = Bsrc[(size_t)k * 256 + j];
    __syncthreads();
    const float* wrow = We2 + (size_t)k * 256;
    float acc = 0.f;
    for (int t = 0; t < 256; ++t) acc += wrow[t] * colB[t];
    Wt[(size_t)j * ldd + koff + k] = f2bf(acc);
}

// bout[j] = base[j]? + sum_k bvec[k] * W[k][j]
__global__ void bvecprod_kernel(const float* __restrict__ base, const float* __restrict__ bvec,
                                const float* __restrict__ W, float* __restrict__ bout)
{
    int j = threadIdx.x;
    float acc = base ? base[j] : 0.f;
    for (int k = 0; k < 256; ++k) acc += bvec[k] * W[(size_t)k * 256 + j];
    bout[j] = acc;
}

// Wt[n*ldd + k] = bf16(W[k][n]);  W: Ksrc x 256 row-major, grid (Ksrc/16, 16)
__global__ void tcast2(const float* __restrict__ W, ushort* __restrict__ Wt, int ldd)
{
    __shared__ float tbuf[16][17];
    int k0 = blockIdx.x * 16, n0 = blockIdx.y * 16;
    int tx = threadIdx.x, ty = threadIdx.y;
    tbuf[ty][tx] = W[(size_t)(k0 + ty) * 256 + n0 + tx];
    __syncthreads();
    Wt[(size_t)(n0 + ty) * ldd + k0 + tx] = f2bf(tbuf[tx][ty]);
}

__global__ void cast_f32_bf16(const float* __restrict__ src, ushort* __restrict__ dst, int n4)
{
    int i = blockIdx.x * 256 + threadIdx.x;
    if (i < n4) {
        float4 v = *reinterpret_cast<const float4*>(src + (size_t)i * 4);
        ushort4 u;
        u.x = f2bf(v.x); u.y = f2bf(v.y); u.z = f2bf(v.z); u.w = f2bf(v.w);
        *reinterpret_cast<ushort4*>(dst + (size_t)i * 4) = u;
    }
}

// sphere rows of nodes (fp32) -> node_in left half (bf16, stride 512)
__global__ void cast_sphere(const float* __restrict__ nodes, ushort* __restrict__ node_in)
{
    int n = blockIdx.x, d = threadIdx.x;
    node_in[(size_t)n * 512 + d] =
        f2bf(nodes[(size_t)(N_SPATIAL_C + n) * 256 + d]);
}

// ---------------------------------------------------------------------------
extern "C" void kernel_launch(void* const* d_in, const int* in_sizes, int n_in,
                              void* d_out, int out_size, void* d_ws, size_t ws_size,
                              hipStream_t stream)
{
    const float* nodes     = (const float*)d_in[0];
    const float* edges3    = (const float*)d_in[1];
    const int*   senders   = (const int*)d_in[2];
    const int*   receivers = (const int*)d_in[3];
    const float* We1a      = (const float*)d_in[4];
    const float* We1b      = (const float*)d_in[5];
    const float* be1       = (const float*)d_in[6];
    const float* ge        = (const float*)d_in[7];
    const float* oe        = (const float*)d_in[8];
    const float* We2       = (const float*)d_in[9];
    const float* be2       = (const float*)d_in[10];
    const float* Wn1       = (const float*)d_in[11];
    const float* bn1       = (const float*)d_in[12];
    const float* gn        = (const float*)d_in[13];
    const float* on_       = (const float*)d_in[14];
    const float* Wn2       = (const float*)d_in[15];
    const float* bn2       = (const float*)d_in[16];

    const float* Ae  = We1a;               // rows 0..2
    const float* As_ = We1a + 3 * 256;     // sender part, step 0
    const float* Ar  = We1a + 259 * 256;   // receiver part, step 0
    const float* Be  = We1b;               // edge part, steps 1,2
    const float* Bs_ = We1b + 256 * 256;   // sender part, steps 1,2
    const float* Br  = We1b + 512 * 256;   // receiver part, steps 1,2
    const float* Wn1bot = Wn1 + 256 * 256; // message part of Wn1

    char* ws = (char*)d_ws;
    size_t off = 0;
    auto alloc = [&](size_t b) -> char* {
        char* p = ws + off;
        off += (b + 255) & ~(size_t)255;
        return p;
    };
    ushort* H          = (ushort*)alloc((size_t)N_EDGES_C * 256 * 2);    // 67 MB
    ushort* Pb         = (ushort*)alloc((size_t)N_SPATIAL_C * 256 * 2);  // 33 MB
    ushort* nodes_bf   = (ushort*)alloc((size_t)N_SPATIAL_C * 256 * 2);  // 33 MB
    float*  Rf         = (float*)alloc((size_t)N_SPHERE_C * 256 * 4);
    ushort* node_in_bf = (ushort*)alloc((size_t)N_SPHERE_C * 512 * 2);   // [sphere|S]
    ushort* nH         = (ushort*)alloc((size_t)N_SPHERE_C * 256 * 2);
    ushort* Ast  = (ushort*)alloc(256 * 256 * 2);
    ushort* Art  = (ushort*)alloc(256 * 256 * 2);
    ushort* Bst  = (ushort*)alloc(256 * 256 * 2);
    ushort* Brt  = (ushort*)alloc(256 * 256 * 2);
    ushort* Wn2t = (ushort*)alloc(256 * 256 * 2);
    ushort* Wft  = (ushort*)alloc(256 * 256 * 2);
    ushort* Bnt  = (ushort*)alloc(256 * 512 * 2);   // [Wn1_top ; We2@Wn1_bot]^T
    float*  bfc  = (float*)alloc(256 * 4);
    float*  bxv  = (float*)alloc(256 * 4);
    int* cnt       = (int*)alloc(N_SPHERE_C * 4);
    int* cursor    = (int*)alloc(N_SPHERE_C * 4);
    int* row_start = (int*)alloc((N_SPHERE_C + 1) * 4);
    int* csr       = (int*)alloc((size_t)N_EDGES_C * 4);

    // CSR build
    hipMemsetAsync(cnt, 0, N_SPHERE_C * 4, stream);
    hipMemsetAsync(cursor, 0, N_SPHERE_C * 4, stream);
    count_k<<<(N_EDGES_C + 255) / 256, 256, 0, stream>>>(receivers, cnt);
    scan_k<<<1, 256, 0, stream>>>(cnt, row_start);
    fill_k<<<(N_EDGES_C + 255) / 256, 256, 0, stream>>>(receivers, row_start, cursor, csr);

    // weight prep
    dim3 tb(16, 16);
    tcast2<<<dim3(16, 16), tb, 0, stream>>>(As_, Ast, 256);
    tcast2<<<dim3(16, 16), tb, 0, stream>>>(Ar,  Art, 256);
    tcast2<<<dim3(16, 16), tb, 0, stream>>>(Bs_, Bst, 256);
    tcast2<<<dim3(16, 16), tb, 0, stream>>>(Br,  Brt, 256);
    tcast2<<<dim3(16, 16), tb, 0, stream>>>(Wn2, Wn2t, 256);
    tcast2<<<dim3(16, 16), tb, 0, stream>>>(Wn1, Bnt, 512);            // top half
    wprod_kernel<<<256, 256, 0, stream>>>(We2, Be, Wft, 256, 0);       // We2@Be ^T
    wprod_kernel<<<256, 256, 0, stream>>>(We2, Wn1bot, Bnt, 512, 256); // We2@Wn1b ^T
    bvecprod_kernel<<<1, 256, 0, stream>>>(be1, be2, Be, bfc);
    bvecprod_kernel<<<1, 256, 0, stream>>>(nullptr, be2, Wn1bot, bxv);

    // input casts
    cast_f32_bf16<<<(N_SPATIAL_C * 64 + 255) / 256, 256, 0, stream>>>(
        nodes, nodes_bf, N_SPATIAL_C * 64);
    cast_sphere<<<N_SPHERE_C, 256, 0, stream>>>(nodes, node_in_bf);

    const int GBIG = 512;
    const int GS = (N_SPHERE_C + 63) / 64;   // 46

    const float* nul = nullptr;

    // P0 = spatial @ As
    mfma_gemm<0, 256, 2, ushort><<<GBIG, 256, 0, stream>>>(
        nodes_bf, Ast, Pb, N_SPATIAL_C, 256, 256,
        nul, nul, nul, nullptr, nullptr, nul, nullptr, nullptr, nul);

    for (int step = 0; step < 3; ++step) {
        // R = sphere @ W1_r  (sphere = node_in left half, lda=512)
        mfma_gemm<0, 256, 2, float><<<GS, 256, 0, stream>>>(
            node_in_bf, step == 0 ? Art : Brt, Rf, N_SPHERE_C, 512, 256,
            nul, nul, nul, nullptr, nullptr, nul, nullptr, nullptr, nul);

        if (step == 0) {
            fuse0<<<N_EDGES_C / 4, 256, 0, stream>>>(
                edges3, Ae, Pb, senders, Rf, receivers, be1, ge, oe, H);
            // overwrite P with P12 = spatial @ Bs
            mfma_gemm<0, 256, 2, ushort><<<GBIG, 256, 0, stream>>>(
                nodes_bf, Bst, Pb, N_SPATIAL_C, 256, 256,
                nul, nul, nul, nullptr, nullptr, nul, nullptr, nullptr, nul);
        } else {
            // H = LN(relu(H@Wf + P12[s] + R[rid] + bfc)) * ge + oe   (in place)
            mfma_gemm<2, 256, 2, ushort><<<GBIG, 256, 0, stream>>>(
                H, Wft, H, N_EDGES_C, 256, 256,
                bfc, ge, oe, Pb, senders, Rf, receivers, nullptr, nul);
        }

        // S = segsum(H) -> node_in right half (stride 512)
        seg_gather<<<N_SPHERE_C, 256, 0, stream>>>(H, row_start, csr,
                                                   node_in_bf + 256, 512);

        // npre = [sphere|S]@Bn + bn1 + cnt*bx ; nH = LN(relu(npre))*gn+on
        mfma_gemm<1, 512, 1, ushort><<<GS, 256, 0, stream>>>(
            node_in_bf, Bnt, nH, N_SPHERE_C, 512, 256,
            bn1, gn, on_, nullptr, nullptr, nul, nullptr, cnt, bxv);

        if (step < 2) {
            // sphere_next = nH@Wn2 + bn2 -> node_in left half (ldc=512)
            mfma_gemm<0, 256, 2, ushort><<<GS, 256, 0, stream>>>(
                nH, Wn2t, node_in_bf, N_SPHERE_C, 256, 512,
                bn2, nul, nul, nullptr, nullptr, nul, nullptr, nullptr, nul);
        } else {
            mfma_gemm<0, 256, 2, float><<<GS, 256, 0, stream>>>(
                nH, Wn2t, (float*)d_out, N_SPHERE_C, 256, 256,
                bn2, nul, nul, nullptr, nullptr, nul, nullptr, nullptr, nul);
        }
    }
}